// Round 1
// baseline (15.511 us; speedup 1.0000x reference)
//
#include <hip/hip_runtime.h>
#include <hip/hip_bf16.h>
#include <math.h>

#define T_STEPS 1024
#define BATCH_N 256
#define HID 8
#define TOT1 (T_STEPS * BATCH_N * HID)   // 2,097,152

// Kernel A: 1 block, 256 threads = 4 waves. Wave w simulates the 8-qubit,
// 2-layer circuit for param set w (pf/pi/pu/po). State = 256 real amplitudes,
// 4 per lane: flat index i = (r<<6) | lane, qubit q <-> bit (7-q).
// Gates on bits 0..5 use __shfl_xor (wave-synchronous, no barriers);
// bits 6..7 are register permutations.
__global__ __launch_bounds__(256) void qlstm_qsim(
    const float* __restrict__ pf, const float* __restrict__ pi_,
    const float* __restrict__ pu, const float* __restrict__ po,
    float* __restrict__ ws) {
  const int tid  = threadIdx.x;
  const int lane = tid & 63;
  const int w    = tid >> 6;
  const float* p = (w == 0) ? pf : (w == 1) ? pi_ : (w == 2) ? pu : po;

  float amp[4];
  amp[0] = (lane == 0) ? 1.0f : 0.0f;   // |0...0>
  amp[1] = 0.0f; amp[2] = 0.0f; amp[3] = 0.0f;

  #pragma unroll
  for (int l = 0; l < 2; ++l) {
    // Ry layer: qubit q acts on flat bit b = 7-q.
    // new0 = c*a0 - s*a1 ; new1 = s*a0 + c*a1 (0/1 = value of that bit)
    #pragma unroll
    for (int q = 0; q < 8; ++q) {
      const int b = 7 - q;
      const float th = 0.5f * p[l * 8 + q];
      const float co = cosf(th), si = sinf(th);
      if (b == 7) {            // register bit 1: pairs (0,2),(1,3)
        float n0 = co * amp[0] - si * amp[2];
        float n2 = si * amp[0] + co * amp[2];
        float n1 = co * amp[1] - si * amp[3];
        float n3 = si * amp[1] + co * amp[3];
        amp[0] = n0; amp[1] = n1; amp[2] = n2; amp[3] = n3;
      } else if (b == 6) {     // register bit 0: pairs (0,1),(2,3)
        float n0 = co * amp[0] - si * amp[1];
        float n1 = si * amp[0] + co * amp[1];
        float n2 = co * amp[2] - si * amp[3];
        float n3 = si * amp[2] + co * amp[3];
        amp[0] = n0; amp[1] = n1; amp[2] = n2; amp[3] = n3;
      } else {                 // lane bit b: shuffle partner
        const int m = 1 << b;
        const bool hi = (lane & m) != 0;
        #pragma unroll
        for (int r = 0; r < 4; ++r) {
          float part = __shfl_xor(amp[r], m, 64);
          amp[r] = hi ? (si * part + co * amp[r])
                      : (co * amp[r] - si * part);
        }
      }
    }
    // CNOT ladder (0,1),(1,2),...,(6,7),(7,0):
    // new[i] = (i has ctrl bit) ? old[i ^ tgt_bit] : old[i]
    #pragma unroll
    for (int q = 0; q < 8; ++q) {
      const int ctrl = q, tgt = (q + 1) & 7;
      const int cb = 7 - ctrl, tb = 7 - tgt;
      if (tb >= 6) {           // target in register bits
        const int rt = 1 << (tb - 6);
        float na[4];
        #pragma unroll
        for (int r = 0; r < 4; ++r) {
          const bool cond = (cb >= 6) ? (((r >> (cb - 6)) & 1) != 0)
                                      : (((lane >> cb) & 1) != 0);
          na[r] = cond ? amp[r ^ rt] : amp[r];
        }
        #pragma unroll
        for (int r = 0; r < 4; ++r) amp[r] = na[r];
      } else {                 // target in lane bits
        const int m = 1 << tb;
        #pragma unroll
        for (int r = 0; r < 4; ++r) {
          float part = __shfl_xor(amp[r], m, 64);
          const bool cond = (cb >= 6) ? (((r >> (cb - 6)) & 1) != 0)
                                      : (((lane >> cb) & 1) != 0);
          amp[r] = cond ? part : amp[r];
        }
      }
    }
  }

  // <Z> on qubit 7 (flat bit 0 = lane bit 0): sum(+-amp^2)
  float v = amp[0] * amp[0] + amp[1] * amp[1] +
            amp[2] * amp[2] + amp[3] * amp[3];
  v = (lane & 1) ? -v : v;
  #pragma unroll
  for (int off = 1; off < 64; off <<= 1) v += __shfl_xor(v, off, 64);

  __shared__ float ev[4];
  if (lane == 0) ev[w] = v;
  __syncthreads();

  // Gate scalars; closed-form recurrence c_t = i*g*(1-f^(t+1))/(1-f).
  // f = sigmoid(ev) in (0.269, 0.731): 1-f bounded away from 0; f^1024
  // underflows cleanly in expf.
  const float f   = 1.0f / (1.0f + expf(-ev[0]));
  const float ii  = 1.0f / (1.0f + expf(-ev[1]));
  const float g   = tanhf(ev[2]);
  const float o   = 1.0f / (1.0f + expf(-ev[3]));
  const float ig  = ii * g;
  const float inv = ig / (1.0f - f);
  const float lf  = logf(f);

  for (int t = tid; t < T_STEPS; t += 256) {
    float c = inv * (1.0f - expf((float)(t + 1) * lf));
    ws[t] = o * tanhf(c);                 // a_t = o*tanh(c_t)
  }
  if (tid == 0) {
    ws[T_STEPS] = inv * (1.0f - expf((float)T_STEPS * lf));  // final cx
  }
}

// Kernel B: broadcast-fill the output. outs[t,b,h] = a_t*rowsum(Wp)[h]+bp[h],
// then hx (= outs[T-1]) and cx (= scalar) blocks. One float4 per thread.
__global__ __launch_bounds__(256) void qlstm_fill(
    const float* __restrict__ wsa, const float* __restrict__ Wp,
    const float* __restrict__ bp, float* __restrict__ out, int out_n) {
  __shared__ float sw[8], sb[8];
  const int tid = threadIdx.x;
  if (tid < 8) {
    float s = 0.0f;
    #pragma unroll
    for (int q = 0; q < 8; ++q) s += Wp[tid * 8 + q];
    sw[tid] = s;
    sb[tid] = bp[tid];
  }
  __syncthreads();

  const int elem = (blockIdx.x * 256 + tid) * 4;
  if (elem >= out_n) return;

  float4 r;
  if (elem < TOT1 + BATCH_N * HID) {
    // outs region (t = elem/2048) or hx region (uses a_{T-1})
    const float at = (elem < TOT1) ? wsa[elem >> 11] : wsa[T_STEPS - 1];
    const int h0 = elem & 7;   // 0 or 4 (regions are 8-aligned)
    r.x = fmaf(at, sw[h0 + 0], sb[h0 + 0]);
    r.y = fmaf(at, sw[h0 + 1], sb[h0 + 1]);
    r.z = fmaf(at, sw[h0 + 2], sb[h0 + 2]);
    r.w = fmaf(at, sw[h0 + 3], sb[h0 + 3]);
  } else {
    const float cf = wsa[T_STEPS];
    r = make_float4(cf, cf, cf, cf);
  }
  *reinterpret_cast<float4*>(out + elem) = r;
}

extern "C" void kernel_launch(void* const* d_in, const int* in_sizes, int n_in,
                              void* d_out, int out_size, void* d_ws, size_t ws_size,
                              hipStream_t stream) {
  // setup_inputs order:
  // 0 inputs, 1 Wf, 2 bf, 3 Wi, 4 bi, 5 Wu, 6 bu, 7 Wo, 8 bo,
  // 9 pf, 10 pi, 11 pu, 12 po, 13 Wp, 14 bp
  const float* pf  = (const float*)d_in[9];
  const float* pi_ = (const float*)d_in[10];
  const float* pu  = (const float*)d_in[11];
  const float* po  = (const float*)d_in[12];
  const float* Wp  = (const float*)d_in[13];
  const float* bp  = (const float*)d_in[14];
  float* out = (float*)d_out;
  float* ws  = (float*)d_ws;   // needs (T_STEPS+1)*4 = 4100 bytes

  qlstm_qsim<<<1, 256, 0, stream>>>(pf, pi_, pu, po, ws);

  const int n4 = out_size / 4;                  // out_size = 2,101,248
  const int blocks = (n4 + 255) / 256;          // 2052
  qlstm_fill<<<blocks, 256, 0, stream>>>(ws, Wp, bp, out, out_size);
}